// Round 1
// baseline (1178.500 us; speedup 1.0000x reference)
//
#include <hip/hip_runtime.h>

// Problem constants
namespace {
constexpr int Bc = 128, Lc = 36, Vc = 36, Dc = 512, KDc = 300, KVc = 112, Qc = 36, Hc = 512;
constexpr int ROWS = Bc * Lc * Vc;     // 165888 rows of (b,l,j)
constexpr int BLn  = Bc * Lc;          // 4608
constexpr int SLOT = Bc * Qc * Qc;     // 165888
constexpr float SCALE = 1.0f / 6.0f;   // 36^-0.5
}

__device__ __forceinline__ float wave_sum(float v) {
  #pragma unroll
  for (int off = 32; off > 0; off >>= 1) v += __shfl_xor(v, off, 64);
  return v;
}
__device__ __forceinline__ float wave_max(float v) {
  #pragma unroll
  for (int off = 32; off > 0; off >>= 1) v = fmaxf(v, __shfl_xor(v, off, 64));
  return v;
}
__device__ __forceinline__ float sigmoidf_(float x) { return 1.f / (1.f + __expf(-x)); }

// csum[b][j][d] = sum_l ctx[b][l][j][d]
__global__ __launch_bounds__(256) void csum_kernel(const float* __restrict__ ctx, float* __restrict__ csum) {
  int tid = blockIdx.x * 256 + threadIdx.x;   // < B*V*D
  int b  = tid / (Vc * Dc);
  int jd = tid % (Vc * Dc);
  const float* p = ctx + (size_t)b * Lc * Vc * Dc + jd;
  float s = 0.f;
  #pragma unroll
  for (int l = 0; l < Lc; ++l) s += p[(size_t)l * (Vc * Dc)];
  csum[tid] = s;
}

// kd[bl][q] = sum_c det[bl][c] * Wk[q][512+c]
__global__ void kd_kernel(const float* __restrict__ det, const float* __restrict__ Wk,
                          float* __restrict__ kd) {
  __shared__ float ds[KDc];
  int bl = blockIdx.x; int t = threadIdx.x;
  for (int c = t; c < KDc; c += 64) ds[c] = det[(size_t)bl * KDc + c];
  __syncthreads();
  if (t < Qc) {
    const float* w = Wk + (size_t)t * 812 + 512;
    float acc = 0.f;
    #pragma unroll 4
    for (int c = 0; c < KDc; ++c) acc = fmaf(ds[c], w[c], acc);
    kd[(size_t)bl * Qc + t] = acc;
  }
}

// k[row][q] = sum_{d<512} ctx_flat[row][d]*Wk[q][d] + kd[row/36][q]
__global__ __launch_bounds__(256) void k_gemm(const float* __restrict__ A, const float* __restrict__ Wk,
                       const float* __restrict__ kd, float* __restrict__ kout) {
  __shared__ __align__(16) float As[32 * 260];
  __shared__ __align__(16) float Bs[32 * 48];
  int t = threadIdx.x;
  int rb = blockIdx.x * 256;
  int tr = t & 63, tc = t >> 6;
  float acc[4][9];
  #pragma unroll
  for (int i = 0; i < 4; ++i)
    #pragma unroll
    for (int c = 0; c < 9; ++c) acc[i][c] = 0.f;

  for (int d0 = 0; d0 < 512; d0 += 32) {
    #pragma unroll
    for (int jj = 0; jj < 8; ++jj) {
      int idx = t + jj * 256;
      int kkb = (idx & 7) * 4, r = idx >> 3;
      const float4 v = *(const float4*)(A + (size_t)(rb + r) * 512 + d0 + kkb);
      As[(kkb + 0) * 260 + r] = v.x;
      As[(kkb + 1) * 260 + r] = v.y;
      As[(kkb + 2) * 260 + r] = v.z;
      As[(kkb + 3) * 260 + r] = v.w;
    }
    for (int idx = t; idx < 32 * 36; idx += 256) {
      int kk = idx / 36, c = idx % 36;
      Bs[kk * 48 + (c / 9) * 12 + (c % 9)] = Wk[(size_t)c * 812 + d0 + kk];
    }
    __syncthreads();
    #pragma unroll
    for (int kk = 0; kk < 32; ++kk) {
      const float4 a  = *(const float4*)&As[kk * 260 + tr * 4];
      const float* bp = &Bs[kk * 48 + tc * 12];
      const float4 b0 = *(const float4*)bp;
      const float4 b1 = *(const float4*)(bp + 4);
      const float  b8 = bp[8];
      const float av[4] = {a.x, a.y, a.z, a.w};
      const float bv[9] = {b0.x, b0.y, b0.z, b0.w, b1.x, b1.y, b1.z, b1.w, b8};
      #pragma unroll
      for (int i = 0; i < 4; ++i)
        #pragma unroll
        for (int c = 0; c < 9; ++c) acc[i][c] = fmaf(av[i], bv[c], acc[i][c]);
    }
    __syncthreads();
  }
  #pragma unroll
  for (int i = 0; i < 4; ++i) {
    int row = rb + tr * 4 + i;
    int bl = row / 36;
    #pragma unroll
    for (int c = 0; c < 9; ++c) {
      int q = tc * 9 + c;
      kout[(size_t)row * 36 + q] = acc[i][c] + kd[(size_t)bl * 36 + q];
    }
  }
}

// generic small GEMM vs Wih: outp[row][c] = sum_k A[row*lda+k] * Wih[c*624 + k0 + k]
__global__ __launch_bounds__(256) void prew_gemm(const float* __restrict__ A, int lda, int K, int k0,
                                                 const float* __restrict__ Wih, float* __restrict__ outp) {
  __shared__ __align__(16) float As[16 * 68];   // [k][row]
  __shared__ __align__(16) float Bs[16 * 112];  // [k][col grouped 28]
  int t = threadIdx.x;
  int rb = blockIdx.x * 64;
  int tr = t & 63, tc = t >> 6;      // tc in 0..3, 27 cols each
  float acc[27];
  #pragma unroll
  for (int c = 0; c < 27; ++c) acc[c] = 0.f;

  for (int kk0 = 0; kk0 < K; kk0 += 16) {
    {
      int r = t >> 2, kq = (t & 3) * 4;
      const float4 v = *(const float4*)(A + (size_t)(rb + r) * lda + kk0 + kq);
      As[(kq + 0) * 68 + r] = v.x;
      As[(kq + 1) * 68 + r] = v.y;
      As[(kq + 2) * 68 + r] = v.z;
      As[(kq + 3) * 68 + r] = v.w;
    }
    for (int idx = t; idx < 16 * 108; idx += 256) {
      int k = idx / 108, c = idx % 108;
      Bs[k * 112 + (c / 27) * 28 + (c % 27)] = Wih[(size_t)c * 624 + k0 + kk0 + k];
    }
    __syncthreads();
    #pragma unroll
    for (int k = 0; k < 16; ++k) {
      const float a = As[k * 68 + tr];
      const float* bp = &Bs[k * 112 + tc * 28];
      float bv[27];
      #pragma unroll
      for (int c4 = 0; c4 < 6; ++c4) {
        float4 b4 = *(const float4*)(bp + c4 * 4);
        bv[c4 * 4 + 0] = b4.x; bv[c4 * 4 + 1] = b4.y; bv[c4 * 4 + 2] = b4.z; bv[c4 * 4 + 3] = b4.w;
      }
      bv[24] = bp[24]; bv[25] = bp[25]; bv[26] = bp[26];
      #pragma unroll
      for (int c = 0; c < 27; ++c) acc[c] = fmaf(a, bv[c], acc[c]);
    }
    __syncthreads();
  }
  int row = rb + tr;
  #pragma unroll
  for (int c = 0; c < 27; ++c)
    outp[(size_t)row * 108 + tc * 27 + c] = acc[c];
}

// ===================== MEGA KERNEL =====================
// One block per batch b (128 blocks x 256 threads). Runs all 3 slot-attention
// iterations in LDS: LN+qsum -> dots+softmax -> (gxmix+GRU fused) -> LN-ff -> MLP.
// Eliminates 19 kernel launches + mid/gx/ffb/slots/qsum global round-trips.
__global__ __launch_bounds__(256) void mega_kernel(
    const float* __restrict__ pano, const float* __restrict__ kmat,
    const float* __restrict__ cw,   const float* __restrict__ gknw,
    const float* __restrict__ Wq,   const float* __restrict__ Whh,
    const float* __restrict__ bih,  const float* __restrict__ bhh,
    const float* __restrict__ lsg,  const float* __restrict__ lsb,
    const float* __restrict__ lfg,  const float* __restrict__ lfb,
    const float* __restrict__ W1,   const float* __restrict__ b1,
    const float* __restrict__ W2,   const float* __restrict__ b2,
    float* __restrict__ out) {
  const int b = blockIdx.x;
  const int t = threadIdx.x;
  const int wv = t >> 6, lane = t & 63;

  // ~107 KB static LDS (gfx950: 160 KB/CU). 1 block/CU.
  __shared__ float s0[36 * 37], s1[36 * 37];      // slots double buffer (pad 37: conflict-free)
  __shared__ float at[36 * 36];                   // attn tile
  __shared__ float cw_s[36 * 108], gk_s[36 * 108];
  __shared__ float whh_s[108 * 37];               // pad 37 -> stride-37 lane reads conflict-free
  __shared__ float ff_s[36 * 37];
  __shared__ float ls4[192];                      // [0..147] wave partials, [148..183] reduced
  __shared__ float qs[36];
  __shared__ __align__(16) float wst[128 * 37];   // W1 chunk [hh][37]; reused as W2 chunk [c][129]
  __shared__ __align__(16) float mid_s[36 * 132]; // relu(mlp1) chunk, pad 132

  // one-time staging (iteration-invariant)
  for (int idx = t; idx < 1296; idx += 256) s0[(idx / 36) * 37 + idx % 36] = pano[idx];
  for (int idx = t; idx < 3888; idx += 256) {
    cw_s[idx] = cw[(size_t)b * 3888 + idx];
    gk_s[idx] = gknw[(size_t)b * 3888 + idx];
    whh_s[(idx / 36) * 37 + idx % 36] = Whh[idx];
  }
  // hoisted per-lane constants
  float gv = 0.f, bv = 0.f, fg = 0.f, fb = 0.f, b2v = 0.f;
  if (lane < 36) { gv = lsg[lane]; bv = lsb[lane]; fg = lfg[lane]; fb = lfb[lane]; b2v = b2[lane]; }
  const float* kb = kmat + (size_t)b * 1296 * 36;
  __syncthreads();

  #pragma unroll
  for (int it = 0; it < 3; ++it) {
    float* cur = (it == 1) ? s1 : s0;
    float* nxt = (it == 1) ? s0 : s1;
    float* aout = out + SLOT + (size_t)it * SLOT + (size_t)b * 1296;

    // ---- phase 1: LN(slots) row-wise, sum over i, then qsum = lnsum @ Wq^T ----
    float lnsum = 0.f;
    #pragma unroll
    for (int ii = 0; ii < 9; ++ii) {
      int i = wv + 4 * ii;
      float x = (lane < 36) ? cur[i * 37 + lane] : 0.f;
      float mu = wave_sum(x) * (1.f / 36.f);
      float d = x - mu;
      float var = wave_sum((lane < 36) ? d * d : 0.f) * (1.f / 36.f);
      float ln = d * rsqrtf(var + 1e-5f) * gv + bv;
      if (lane < 36) lnsum += ln;
    }
    if (lane < 36) ls4[wv * 37 + lane] = lnsum;
    __syncthreads();
    if (t < 36) {
      float l0 = ls4[t] + ls4[37 + t] + ls4[74 + t] + ls4[111 + t];
      ls4[148 + t] = l0;
    }
    if (t < 36) {  // same wave -> LDS write/read ordered within wave
      float acc = 0.f;
      #pragma unroll
      for (int e = 0; e < 36; ++e) acc = fmaf(ls4[148 + e], Wq[t * 36 + e], acc);
      qs[t] = acc;
    }
    __syncthreads();

    // ---- phase 2: dots (qsum . k) + softmax over views j; write attn ----
    #pragma unroll
    for (int ii = 0; ii < 9; ++ii) {
      int l = wv * 9 + ii;
      float dot = 0.f;
      if (lane < 36) {
        const float* kp = kb + ((size_t)l * 36 + lane) * 36;
        #pragma unroll
        for (int c = 0; c < 9; ++c) {
          float4 kv = *(const float4*)(kp + 4 * c);
          dot += kv.x * qs[4 * c] + kv.y * qs[4 * c + 1] + kv.z * qs[4 * c + 2] + kv.w * qs[4 * c + 3];
        }
      }
      dot *= SCALE;
      float m = wave_max((lane < 36) ? dot : -1e30f);
      float e = (lane < 36) ? __expf(dot - m) : 0.f;
      float s = wave_sum(e);
      if (lane < 36) {
        float a = e / s;
        at[l * 36 + lane] = a;
        aout[(size_t)l * 36 + lane] = a;
      }
    }
    __syncthreads();

    // ---- phase 3: fused gxmix + GRU gate ----
    // gx[i][c+g*36] = sum_j at[i][j]*cw[j][c+g*36] + gknw[i][c+g*36]; then GRU.
    for (int idx = t; idx < 1296; idx += 256) {
      int i = idx / 36, c = idx % 36;
      const float* ar = &at[i * 36];
      float xr = gk_s[i * 108 + c]      + bih[c];
      float xz = gk_s[i * 108 + 36 + c] + bih[36 + c];
      float xn = gk_s[i * 108 + 72 + c] + bih[72 + c];
      #pragma unroll 4
      for (int j = 0; j < 36; ++j) {
        float a = ar[j];
        xr = fmaf(a, cw_s[j * 108 + c],      xr);
        xz = fmaf(a, cw_s[j * 108 + 36 + c], xz);
        xn = fmaf(a, cw_s[j * 108 + 72 + c], xn);
      }
      float hr = bhh[c], hz = bhh[36 + c], hn = bhh[72 + c];
      const float* hrow = &cur[i * 37];
      #pragma unroll 4
      for (int e = 0; e < 36; ++e) {
        float h = hrow[e];
        hr = fmaf(h, whh_s[c * 37 + e],        hr);
        hz = fmaf(h, whh_s[(36 + c) * 37 + e], hz);
        hn = fmaf(h, whh_s[(72 + c) * 37 + e], hn);
      }
      float r = sigmoidf_(xr + hr), z = sigmoidf_(xz + hz);
      float n = tanhf(xn + r * hn);
      nxt[i * 37 + c] = (1.f - z) * n + z * hrow[c];
    }
    __syncthreads();

    // ---- phase 4: LN-ff per row; snew init = hprime + b2 ----
    #pragma unroll
    for (int ii = 0; ii < 9; ++ii) {
      int i = wv * 9 + ii;
      float v = (lane < 36) ? nxt[i * 37 + lane] : 0.f;
      float mu = wave_sum(v) * (1.f / 36.f);
      float d = v - mu;
      float var = wave_sum((lane < 36) ? d * d : 0.f) * (1.f / 36.f);
      float rstd = rsqrtf(var + 1e-5f);
      if (lane < 36) {
        ff_s[i * 37 + lane] = d * rstd * fg + fb;
        nxt[i * 37 + lane] = v + b2v;
      }
    }
    __syncthreads();

    // ---- phase 5: MLP, H chunked by 128; mid stays in LDS ----
    float acc[6] = {0.f, 0.f, 0.f, 0.f, 0.f, 0.f};
    for (int h0 = 0; h0 < 512; h0 += 128) {
      // stage W1 chunk [hh][e] padded 37
      for (int idx = t; idx < 4608; idx += 256)
        wst[(idx / 36) * 37 + idx % 36] = W1[(size_t)h0 * 36 + idx];
      __syncthreads();
      // mid[i][hh] = relu(ff . W1row + b1)
      for (int idx = t; idx < 4608; idx += 256) {
        int i = idx >> 7, hh = idx & 127;
        float a = b1[h0 + hh];
        const float* fr = &ff_s[i * 37];
        const float* wr = &wst[hh * 37];
        #pragma unroll 4
        for (int e = 0; e < 36; ++e) a = fmaf(fr[e], wr[e], a);
        mid_s[i * 132 + hh] = fmaxf(a, 0.f);
      }
      __syncthreads();
      // stage W2 chunk [c][hh] padded 129 (bank = (c+hh)%32, conflict-free)
      for (int idx = t; idx < 4608; idx += 256)
        wst[(idx >> 7) * 129 + (idx & 127)] = W2[(size_t)(idx >> 7) * 512 + h0 + (idx & 127)];
      __syncthreads();
      // accumulate snew partial
      #pragma unroll
      for (int pi = 0; pi < 6; ++pi) {
        int idx = t + pi * 256;
        if (idx < 1296) {
          int i = idx / 36, c = idx % 36;
          const float* mr = &mid_s[i * 132];
          const float* wr = &wst[c * 129];
          float a = acc[pi];
          #pragma unroll 4
          for (int hh = 0; hh < 128; ++hh) a = fmaf(mr[hh], wr[hh], a);
          acc[pi] = a;
        }
      }
      __syncthreads();
    }
    #pragma unroll
    for (int pi = 0; pi < 6; ++pi) {
      int idx = t + pi * 256;
      if (idx < 1296) nxt[(idx / 36) * 37 + idx % 36] += acc[pi];
    }
    __syncthreads();
  }

  // final slots (after 3 iters result is in s1)
  for (int idx = t; idx < 1296; idx += 256)
    out[(size_t)b * 1296 + idx] = s1[(idx / 36) * 37 + idx % 36];
}

extern "C" void kernel_launch(void* const* d_in, const int* in_sizes, int n_in,
                              void* d_out, int out_size, void* d_ws, size_t ws_size,
                              hipStream_t stream) {
  const float* ctx  = (const float*)d_in[1];
  const float* det  = (const float*)d_in[3];
  const float* knw  = (const float*)d_in[4];
  const float* pano = (const float*)d_in[5];
  const float* Wq   = (const float*)d_in[6];
  const float* Wk   = (const float*)d_in[7];
  const float* Wih  = (const float*)d_in[8];
  const float* Whh  = (const float*)d_in[9];
  const float* bih  = (const float*)d_in[10];
  const float* bhh  = (const float*)d_in[11];
  const float* lsg  = (const float*)d_in[12];
  const float* lsb  = (const float*)d_in[13];
  const float* lfg  = (const float*)d_in[14];
  const float* lfb  = (const float*)d_in[15];
  const float* W1   = (const float*)d_in[16];
  const float* b1   = (const float*)d_in[17];
  const float* W2   = (const float*)d_in[18];
  const float* b2   = (const float*)d_in[19];
  float* out = (float*)d_out;

  float* w = (float*)d_ws;
  float* kmat = w; w += (size_t)ROWS * 36;      // 24 MB
  float* csum = w; w += (size_t)Bc * Vc * Dc;   // 9.4 MB
  float* kd   = w; w += (size_t)BLn * Qc;
  float* cw   = w; w += (size_t)BLn * 108;
  float* gknw = w; w += (size_t)BLn * 108;

  csum_kernel<<<(Bc * Vc * Dc) / 256, 256, 0, stream>>>(ctx, csum);
  kd_kernel<<<BLn, 64, 0, stream>>>(det, Wk, kd);
  k_gemm<<<ROWS / 256, 256, 0, stream>>>(ctx, Wk, kd, kmat);
  prew_gemm<<<72, 256, 0, stream>>>(csum, 512, 512, 0,   Wih, cw);    // cw  = csum @ Wih[:,:512]^T
  prew_gemm<<<72, 256, 0, stream>>>(knw,  112, 112, 512, Wih, gknw);  // gknw = knw @ Wih[:,512:]^T
  mega_kernel<<<Bc, 256, 0, stream>>>(pano, kmat, cw, gknw, Wq, Whh, bih, bhh,
                                      lsg, lsb, lfg, lfb, W1, b1, W2, b2, out);
}

// Round 2
// 1103.967 us; speedup vs baseline: 1.0675x; 1.0675x over previous
//
#include <hip/hip_runtime.h>

// Problem constants
namespace {
constexpr int Bc = 128, Lc = 36, Vc = 36, Dc = 512, KDc = 300, KVc = 112, Qc = 36, Hc = 512;
constexpr int ROWS = Bc * Lc * Vc;     // 165888 rows of (b,l,j)
constexpr int BLn  = Bc * Lc;          // 4608
constexpr int SLOT = Bc * Qc * Qc;     // 165888
constexpr float SCALE = 1.0f / 6.0f;   // 36^-0.5
}

__device__ __forceinline__ float wave_sum(float v) {
  #pragma unroll
  for (int off = 32; off > 0; off >>= 1) v += __shfl_xor(v, off, 64);
  return v;
}
__device__ __forceinline__ float wave_max(float v) {
  #pragma unroll
  for (int off = 32; off > 0; off >>= 1) v = fmaxf(v, __shfl_xor(v, off, 64));
  return v;
}
__device__ __forceinline__ float sigmoidf_(float x) { return 1.f / (1.f + __expf(-x)); }
__device__ __forceinline__ float dot4_(float4 a, float4 b) {
  return fmaf(a.x, b.x, fmaf(a.y, b.y, fmaf(a.z, b.z, a.w * b.w)));
}

// csum[b][j][d] = sum_l ctx[b][l][j][d]
__global__ __launch_bounds__(256) void csum_kernel(const float* __restrict__ ctx, float* __restrict__ csum) {
  int tid = blockIdx.x * 256 + threadIdx.x;   // < B*V*D
  int b  = tid / (Vc * Dc);
  int jd = tid % (Vc * Dc);
  const float* p = ctx + (size_t)b * Lc * Vc * Dc + jd;
  float s = 0.f;
  #pragma unroll
  for (int l = 0; l < Lc; ++l) s += p[(size_t)l * (Vc * Dc)];
  csum[tid] = s;
}

// kd[bl][q] = sum_c det[bl][c] * Wk[q][512+c]
__global__ void kd_kernel(const float* __restrict__ det, const float* __restrict__ Wk,
                          float* __restrict__ kd) {
  __shared__ float ds[KDc];
  int bl = blockIdx.x; int t = threadIdx.x;
  for (int c = t; c < KDc; c += 64) ds[c] = det[(size_t)bl * KDc + c];
  __syncthreads();
  if (t < Qc) {
    const float* w = Wk + (size_t)t * 812 + 512;
    float acc = 0.f;
    #pragma unroll 4
    for (int c = 0; c < KDc; ++c) acc = fmaf(ds[c], w[c], acc);
    kd[(size_t)bl * Qc + t] = acc;
  }
}

// k[row][q] = sum_{d<512} ctx_flat[row][d]*Wk[q][d] + kd[row/36][q]
__global__ __launch_bounds__(256) void k_gemm(const float* __restrict__ A, const float* __restrict__ Wk,
                       const float* __restrict__ kd, float* __restrict__ kout) {
  __shared__ __align__(16) float As[32 * 260];
  __shared__ __align__(16) float Bs[32 * 48];
  int t = threadIdx.x;
  int rb = blockIdx.x * 256;
  int tr = t & 63, tc = t >> 6;
  float acc[4][9];
  #pragma unroll
  for (int i = 0; i < 4; ++i)
    #pragma unroll
    for (int c = 0; c < 9; ++c) acc[i][c] = 0.f;

  for (int d0 = 0; d0 < 512; d0 += 32) {
    #pragma unroll
    for (int jj = 0; jj < 8; ++jj) {
      int idx = t + jj * 256;
      int kkb = (idx & 7) * 4, r = idx >> 3;
      const float4 v = *(const float4*)(A + (size_t)(rb + r) * 512 + d0 + kkb);
      As[(kkb + 0) * 260 + r] = v.x;
      As[(kkb + 1) * 260 + r] = v.y;
      As[(kkb + 2) * 260 + r] = v.z;
      As[(kkb + 3) * 260 + r] = v.w;
    }
    for (int idx = t; idx < 32 * 36; idx += 256) {
      int kk = idx / 36, c = idx % 36;
      Bs[kk * 48 + (c / 9) * 12 + (c % 9)] = Wk[(size_t)c * 812 + d0 + kk];
    }
    __syncthreads();
    #pragma unroll
    for (int kk = 0; kk < 32; ++kk) {
      const float4 a  = *(const float4*)&As[kk * 260 + tr * 4];
      const float* bp = &Bs[kk * 48 + tc * 12];
      const float4 b0 = *(const float4*)bp;
      const float4 b1 = *(const float4*)(bp + 4);
      const float  b8 = bp[8];
      const float av[4] = {a.x, a.y, a.z, a.w};
      const float bv[9] = {b0.x, b0.y, b0.z, b0.w, b1.x, b1.y, b1.z, b1.w, b8};
      #pragma unroll
      for (int i = 0; i < 4; ++i)
        #pragma unroll
        for (int c = 0; c < 9; ++c) acc[i][c] = fmaf(av[i], bv[c], acc[i][c]);
    }
    __syncthreads();
  }
  #pragma unroll
  for (int i = 0; i < 4; ++i) {
    int row = rb + tr * 4 + i;
    int bl = row / 36;
    #pragma unroll
    for (int c = 0; c < 9; ++c) {
      int q = tc * 9 + c;
      kout[(size_t)row * 36 + q] = acc[i][c] + kd[(size_t)bl * 36 + q];
    }
  }
}

// generic small GEMM vs Wih: outp[row][c] = sum_k A[row*lda+k] * Wih[c*624 + k0 + k]
__global__ __launch_bounds__(256) void prew_gemm(const float* __restrict__ A, int lda, int K, int k0,
                                                 const float* __restrict__ Wih, float* __restrict__ outp) {
  __shared__ __align__(16) float As[16 * 68];   // [k][row]
  __shared__ __align__(16) float Bs[16 * 112];  // [k][col grouped 28]
  int t = threadIdx.x;
  int rb = blockIdx.x * 64;
  int tr = t & 63, tc = t >> 6;      // tc in 0..3, 27 cols each
  float acc[27];
  #pragma unroll
  for (int c = 0; c < 27; ++c) acc[c] = 0.f;

  for (int kk0 = 0; kk0 < K; kk0 += 16) {
    {
      int r = t >> 2, kq = (t & 3) * 4;
      const float4 v = *(const float4*)(A + (size_t)(rb + r) * lda + kk0 + kq);
      As[(kq + 0) * 68 + r] = v.x;
      As[(kq + 1) * 68 + r] = v.y;
      As[(kq + 2) * 68 + r] = v.z;
      As[(kq + 3) * 68 + r] = v.w;
    }
    for (int idx = t; idx < 16 * 108; idx += 256) {
      int k = idx / 108, c = idx % 108;
      Bs[k * 112 + (c / 27) * 28 + (c % 27)] = Wih[(size_t)c * 624 + k0 + kk0 + k];
    }
    __syncthreads();
    #pragma unroll
    for (int k = 0; k < 16; ++k) {
      const float a = As[k * 68 + tr];
      const float* bp = &Bs[k * 112 + tc * 28];
      float bv[27];
      #pragma unroll
      for (int c4 = 0; c4 < 6; ++c4) {
        float4 b4 = *(const float4*)(bp + c4 * 4);
        bv[c4 * 4 + 0] = b4.x; bv[c4 * 4 + 1] = b4.y; bv[c4 * 4 + 2] = b4.z; bv[c4 * 4 + 3] = b4.w;
      }
      bv[24] = bp[24]; bv[25] = bp[25]; bv[26] = bp[26];
      #pragma unroll
      for (int c = 0; c < 27; ++c) acc[c] = fmaf(a, bv[c], acc[c]);
    }
    __syncthreads();
  }
  int row = rb + tr;
  #pragma unroll
  for (int c = 0; c < 27; ++c)
    outp[(size_t)row * 108 + tc * 27 + c] = acc[c];
}

// ===================== MEGA KERNEL (512 threads, reg-tiled, vectorized) =====================
__global__ __launch_bounds__(512) void mega_kernel(
    const float* __restrict__ pano, const float* __restrict__ kmat,
    const float* __restrict__ cw,   const float* __restrict__ gknw,
    const float* __restrict__ Wq,   const float* __restrict__ Whh,
    const float* __restrict__ bih,  const float* __restrict__ bhh,
    const float* __restrict__ lsg,  const float* __restrict__ lsb,
    const float* __restrict__ lfg,  const float* __restrict__ lfb,
    const float* __restrict__ W1,   const float* __restrict__ b1,
    const float* __restrict__ W2,   const float* __restrict__ b2,
    float* __restrict__ out) {
  const int b = blockIdx.x;
  const int t = threadIdx.x;
  const int wv = t >> 6, lane = t & 63;

  // ~93 KB LDS, 1 block/CU, 8 waves (2/SIMD)
  __shared__ __align__(16) float s0[36 * 40], s1[36 * 40];  // slots dbuf, pad 40 (16B-aligned rows)
  __shared__ float at[36 * 36];
  __shared__ __align__(16) float cw_s[36 * 108], gk_s[36 * 108];
  __shared__ __align__(16) float whh_s[108 * 44];           // pad 44: aligned + bank-spread
  __shared__ __align__(16) float ff_s[36 * 40];
  __shared__ float ls8[8 * 37];
  __shared__ float qs[36];
  __shared__ __align__(16) float mid_s[36 * 132];           // mlp1 chunk (128 wide)

  // ---- one-time staging ----
  for (int q4 = t; q4 < 972; q4 += 512) {                   // cw/gknw vectorized
    *(float4*)&cw_s[q4 * 4] = *(const float4*)(cw   + (size_t)b * 3888 + q4 * 4);
    *(float4*)&gk_s[q4 * 4] = *(const float4*)(gknw + (size_t)b * 3888 + q4 * 4);
  }
  for (int idx = t; idx < 3888; idx += 512)
    whh_s[(idx / 36) * 44 + idx % 36] = Whh[idx];
  for (int idx = t; idx < 1296; idx += 512)
    s0[(idx / 36) * 40 + idx % 36] = pano[idx];
  float gv = 0.f, bv = 0.f, fg = 0.f, fb = 0.f, b2v = 0.f;
  if (lane < 36) { gv = lsg[lane]; bv = lsb[lane]; fg = lfg[lane]; fb = lfb[lane]; b2v = b2[lane]; }
  const float* kb = kmat + (size_t)b * 1296 * 36;
  __syncthreads();

  for (int it = 0; it < 3; ++it) {
    float* cur = (it == 1) ? s1 : s0;
    float* nxt = (it == 1) ? s0 : s1;
    float* aout = out + SLOT + (size_t)it * SLOT + (size_t)b * 1296;

    // ---- phase 1: LN(slots) rows over 8 waves; qsum = (sum_i LN_i) @ Wq^T ----
    float lnsum = 0.f;
    #pragma unroll
    for (int ii = 0; ii < 5; ++ii) {
      int i = wv + 8 * ii;
      bool act = (i < 36) && (lane < 36);
      float x = act ? cur[i * 40 + lane] : 0.f;
      float mu = wave_sum(x) * (1.f / 36.f);
      float d = x - mu;
      float var = wave_sum(act ? d * d : 0.f) * (1.f / 36.f);
      float ln = d * rsqrtf(var + 1e-5f) * gv + bv;
      if (act) lnsum += ln;
    }
    if (lane < 36) ls8[wv * 37 + lane] = lnsum;
    __syncthreads();
    if (t < 36) {
      float l0 = 0.f;
      #pragma unroll
      for (int w = 0; w < 8; ++w) l0 += ls8[w * 37 + t];
      ls8[8 * 37 - 37 + t] = 0.f;  // unused slot; keep ls8 live
      float acc = 0.f;
      // need full lnsum vector: recompute via LDS broadcast after writing
      ls8[296 - 296 + t] = l0;     // reuse row 0 as the reduced vector
    }
    __syncthreads();
    if (t < 36) {
      float acc = 0.f;
      #pragma unroll
      for (int e = 0; e < 36; ++e) acc = fmaf(ls8[e], Wq[t * 36 + e], acc);
      qs[t] = acc;
    }
    __syncthreads();

    // ---- phase 2: dots + softmax over views; rows over 8 waves ----
    #pragma unroll
    for (int ii = 0; ii < 5; ++ii) {
      int l = wv + 8 * ii;
      if (l < 36) {
        float dot = 0.f;
        if (lane < 36) {
          const float* kp = kb + ((size_t)l * 36 + lane) * 36;
          #pragma unroll
          for (int c = 0; c < 9; ++c) {
            float4 kv = *(const float4*)(kp + 4 * c);
            dot += kv.x * qs[4 * c] + kv.y * qs[4 * c + 1] + kv.z * qs[4 * c + 2] + kv.w * qs[4 * c + 3];
          }
        }
        dot *= SCALE;
        float m = wave_max((lane < 36) ? dot : -1e30f);
        float e = (lane < 36) ? __expf(dot - m) : 0.f;
        float s = wave_sum(e);
        if (lane < 36) {
          float a = e / s;
          at[l * 36 + lane] = a;
          aout[(size_t)l * 36 + lane] = a;
        }
      }
    }
    __syncthreads();

    // ---- phase 3: fused gxmix + GRU, 2i x 2c register tiles ----
    if (t < 324) {
      int i0 = (t / 18) * 2, c0 = (t % 18) * 2;
      float ax[3][2][2], ah[3][2][2];
      #pragma unroll
      for (int g = 0; g < 3; ++g)
        #pragma unroll
        for (int r = 0; r < 2; ++r)
          #pragma unroll
          for (int cc = 0; cc < 2; ++cc) {
            ax[g][r][cc] = gk_s[(i0 + r) * 108 + g * 36 + c0 + cc] + bih[g * 36 + c0 + cc];
            ah[g][r][cc] = bhh[g * 36 + c0 + cc];
          }
      #pragma unroll 4
      for (int j = 0; j < 36; ++j) {
        float a0 = at[i0 * 36 + j], a1 = at[(i0 + 1) * 36 + j];
        #pragma unroll
        for (int g = 0; g < 3; ++g)
          #pragma unroll
          for (int cc = 0; cc < 2; ++cc) {
            float wjc = cw_s[j * 108 + g * 36 + c0 + cc];
            ax[g][0][cc] = fmaf(a0, wjc, ax[g][0][cc]);
            ax[g][1][cc] = fmaf(a1, wjc, ax[g][1][cc]);
          }
      }
      #pragma unroll
      for (int eq = 0; eq < 9; ++eq) {
        float4 h0q = *(const float4*)&cur[i0 * 40 + eq * 4];
        float4 h1q = *(const float4*)&cur[(i0 + 1) * 40 + eq * 4];
        #pragma unroll
        for (int g = 0; g < 3; ++g)
          #pragma unroll
          for (int cc = 0; cc < 2; ++cc) {
            float4 wq4 = *(const float4*)&whh_s[(g * 36 + c0 + cc) * 44 + eq * 4];
            ah[g][0][cc] += dot4_(h0q, wq4);
            ah[g][1][cc] += dot4_(h1q, wq4);
          }
      }
      #pragma unroll
      for (int r = 0; r < 2; ++r)
        #pragma unroll
        for (int cc = 0; cc < 2; ++cc) {
          int i = i0 + r, c = c0 + cc;
          float hp = cur[i * 40 + c];
          float rr = sigmoidf_(ax[0][r][cc] + ah[0][r][cc]);
          float zz = sigmoidf_(ax[1][r][cc] + ah[1][r][cc]);
          float nn = tanhf(ax[2][r][cc] + rr * ah[2][r][cc]);
          nxt[i * 40 + c] = (1.f - zz) * nn + zz * hp;
        }
    }
    __syncthreads();

    // ---- phase 4: LN-ff rows over 8 waves; snew init = hprime + b2 ----
    #pragma unroll
    for (int ii = 0; ii < 5; ++ii) {
      int i = wv + 8 * ii;
      if (i < 36) {
        float v = (lane < 36) ? nxt[i * 40 + lane] : 0.f;
        float mu = wave_sum(v) * (1.f / 36.f);
        float d = v - mu;
        float var = wave_sum((lane < 36) ? d * d : 0.f) * (1.f / 36.f);
        float rstd = rsqrtf(var + 1e-5f);
        if (lane < 36) {
          ff_s[i * 40 + lane] = d * rstd * fg + fb;
          nxt[i * 40 + lane] = v + b2v;
        }
      }
    }
    __syncthreads();

    // ---- phase 5: MLP, H chunked by 128, W1/W2 direct from global (L1/L2) ----
    float acc2[2][2] = {{0.f, 0.f}, {0.f, 0.f}};
    for (int h0 = 0; h0 < 512; h0 += 128) {
      // mlp1: 3i x 4hh register tile, 384 active threads
      if (t < 384) {
        int ig = t >> 5, hq = t & 31;
        int i_0 = ig * 3;
        int hh = h0 + hq * 4;
        float4 bq = *(const float4*)&b1[hh];
        float m[3][4] = {{bq.x, bq.y, bq.z, bq.w},
                         {bq.x, bq.y, bq.z, bq.w},
                         {bq.x, bq.y, bq.z, bq.w}};
        const float* w1p = W1 + (size_t)hh * 36;
        #pragma unroll
        for (int eq = 0; eq < 9; ++eq) {
          float4 f0 = *(const float4*)&ff_s[i_0 * 40 + eq * 4];
          float4 f1 = *(const float4*)&ff_s[(i_0 + 1) * 40 + eq * 4];
          float4 f2 = *(const float4*)&ff_s[(i_0 + 2) * 40 + eq * 4];
          #pragma unroll
          for (int c = 0; c < 4; ++c) {
            float4 wq4 = *(const float4*)(w1p + (size_t)c * 36 + eq * 4);
            m[0][c] += dot4_(f0, wq4);
            m[1][c] += dot4_(f1, wq4);
            m[2][c] += dot4_(f2, wq4);
          }
        }
        #pragma unroll
        for (int r = 0; r < 3; ++r) {
          float4 o;
          o.x = fmaxf(m[r][0], 0.f); o.y = fmaxf(m[r][1], 0.f);
          o.z = fmaxf(m[r][2], 0.f); o.w = fmaxf(m[r][3], 0.f);
          *(float4*)&mid_s[(i_0 + r) * 132 + hq * 4] = o;
        }
      }
      __syncthreads();
      // mlp2: 2i x 2c register tile, 324 active threads, acc carried across chunks
      if (t < 324) {
        int i0 = (t / 18) * 2, c0 = (t % 18) * 2;
        const float* w2a = W2 + (size_t)c0 * 512 + h0;
        const float* w2b = W2 + (size_t)(c0 + 1) * 512 + h0;
        #pragma unroll 8
        for (int kq = 0; kq < 32; ++kq) {
          float4 m0 = *(const float4*)&mid_s[i0 * 132 + kq * 4];
          float4 m1 = *(const float4*)&mid_s[(i0 + 1) * 132 + kq * 4];
          float4 w0 = *(const float4*)(w2a + kq * 4);
          float4 w1 = *(const float4*)(w2b + kq * 4);
          acc2[0][0] += dot4_(m0, w0);
          acc2[0][1] += dot4_(m0, w1);
          acc2[1][0] += dot4_(m1, w0);
          acc2[1][1] += dot4_(m1, w1);
        }
      }
      __syncthreads();  // mid consumed before next chunk overwrites
    }
    if (t < 324) {
      int i0 = (t / 18) * 2, c0 = (t % 18) * 2;
      nxt[i0 * 40 + c0]             += acc2[0][0];
      nxt[i0 * 40 + c0 + 1]         += acc2[0][1];
      nxt[(i0 + 1) * 40 + c0]       += acc2[1][0];
      nxt[(i0 + 1) * 40 + c0 + 1]   += acc2[1][1];
    }
    __syncthreads();
  }

  // final slots (after 3 iters result is in s1), vectorized store
  for (int v4 = t; v4 < 324; v4 += 512) {
    int row = v4 / 9, q = v4 % 9;
    *(float4*)&out[(size_t)b * 1296 + row * 36 + q * 4] = *(const float4*)&s1[row * 40 + q * 4];
  }
}

extern "C" void kernel_launch(void* const* d_in, const int* in_sizes, int n_in,
                              void* d_out, int out_size, void* d_ws, size_t ws_size,
                              hipStream_t stream) {
  const float* ctx  = (const float*)d_in[1];
  const float* det  = (const float*)d_in[3];
  const float* knw  = (const float*)d_in[4];
  const float* pano = (const float*)d_in[5];
  const float* Wq   = (const float*)d_in[6];
  const float* Wk   = (const float*)d_in[7];
  const float* Wih  = (const float*)d_in[8];
  const float* Whh  = (const float*)d_in[9];
  const float* bih  = (const float*)d_in[10];
  const float* bhh  = (const float*)d_in[11];
  const float* lsg  = (const float*)d_in[12];
  const float* lsb  = (const float*)d_in[13];
  const float* lfg  = (const float*)d_in[14];
  const float* lfb  = (const float*)d_in[15];
  const float* W1   = (const float*)d_in[16];
  const float* b1   = (const float*)d_in[17];
  const float* W2   = (const float*)d_in[18];
  const float* b2   = (const float*)d_in[19];
  float* out = (float*)d_out;

  float* w = (float*)d_ws;
  float* kmat = w; w += (size_t)ROWS * 36;      // 24 MB
  float* csum = w; w += (size_t)Bc * Vc * Dc;   // 9.4 MB
  float* kd   = w; w += (size_t)BLn * Qc;
  float* cw   = w; w += (size_t)BLn * 108;
  float* gknw = w; w += (size_t)BLn * 108;

  csum_kernel<<<(Bc * Vc * Dc) / 256, 256, 0, stream>>>(ctx, csum);
  kd_kernel<<<BLn, 64, 0, stream>>>(det, Wk, kd);
  k_gemm<<<ROWS / 256, 256, 0, stream>>>(ctx, Wk, kd, kmat);
  prew_gemm<<<72, 256, 0, stream>>>(csum, 512, 512, 0,   Wih, cw);    // cw  = csum @ Wih[:,:512]^T
  prew_gemm<<<72, 256, 0, stream>>>(knw,  112, 112, 512, Wih, gknw);  // gknw = knw @ Wih[:,512:]^T
  mega_kernel<<<Bc, 512, 0, stream>>>(pano, kmat, cw, gknw, Wq, Whh, bih, bhh,
                                      lsg, lsb, lfg, lfb, W1, b1, W2, b2, out);
}